// Round 7
// baseline (41.461 us; speedup 1.0000x reference)
//
#include <hip/hip_runtime.h>
#include <math.h>

// Problem constants (from the reference file)
constexpr int B_   = 128;
constexpr int S_   = 2048;
constexpr int EMB_ = 128;
constexpr int HID_ = 256;
constexpr int OUT_ = 32;

constexpr int HT   = 8;         // h per block (round-3 proven geometry)
constexpr int BH   = 64;        // b per block (half the batch)
constexpr int PADK = EMB_ + 4;  // 132: 16B-aligned rows, stride%32==4 -> conflict-free b128
constexpr int NBLK = 128;       // 2 dirs x 32 h-tiles x 2 b-halves

// ws layout:
//   [0, 1MB)  : pl[sl64][bhalf][64][32] f32 partial logits, slice-major ->
//               each block writes one contiguous 8KB chunk (coalesced).
//   [1MB]     : u32 arrival counter (4-byte memset each call)
constexpr size_t CTR_OFF = 1ull << 20;

__global__ __launch_bounds__(512) void bilstm_one(
    const int*   __restrict__ inputs,
    const float* __restrict__ weight,
    const float* __restrict__ Wxf, const float* __restrict__ bxf, const float* __restrict__ bhf,
    const float* __restrict__ Wxb, const float* __restrict__ bxb, const float* __restrict__ bhb,
    const float* __restrict__ Why, const float* __restrict__ by,
    float*        __restrict__ pl,
    unsigned int* __restrict__ ctr,
    float*        __restrict__ out)
{
    __shared__ __align__(16) float Xs[BH][PADK];      // 33.8 KB (tail reuses as red[64][8] float4)
    __shared__ __align__(16) float Ws[3][HT][PADK];   // 12.7 KB
    __shared__ float Whys[OUT_][9];                   // stride 9: conflict-free
    __shared__ float hy_s[BH][HT];
    __shared__ int   toks[BH];
    __shared__ float lg[OUT_];

    const int blk   = blockIdx.x;
    const int dir   = blk >> 6;          // 64 blocks per direction
    const int ht    = (blk & 63) >> 1;   // 0..31
    const int bhalf = blk & 1;
    const int h0    = ht * HT;
    const int tid   = threadIdx.x;

    if (tid < BH)
        toks[tid] = inputs[(size_t)(bhalf * BH + tid) * S_ + (dir ? 0 : (S_ - 1))];
    __syncthreads();

    // ---- stage X: 64 rows x 32 float4, 4 passes of 512
    #pragma unroll
    for (int p = 0; p < 4; ++p) {
        const int idx = p * 512 + tid;
        const int bl  = idx >> 5;
        const int j   = idx & 31;
        const float4 v = reinterpret_cast<const float4*>(weight + (size_t)toks[bl] * EMB_)[j];
        *reinterpret_cast<float4*>(&Xs[bl][4 * j]) = v;
    }
    // ---- stage W: 3 gates x 8 rows x 32 float4
    {
        const float* Wx = dir ? Wxb : Wxf;
        for (int idx = tid; idx < 3 * HT * 32; idx += 512) {
            const int g   = idx >> 8;
            const int rem = idx & 255;
            const int hl  = rem >> 5;
            const int j   = rem & 31;
            const int grow = (g == 0) ? 0 : ((g == 1) ? 2 : 3);  // i, g, o rows
            const float4 v = reinterpret_cast<const float4*>(
                Wx + (size_t)(grow * HID_ + h0 + hl) * EMB_)[j];
            *reinterpret_cast<float4*>(&Ws[g][hl][4 * j]) = v;
        }
    }
    // ---- stage Why tile: [32 o][8 hl]
    if (tid < OUT_ * HT) {
        const int o  = tid >> 3;
        const int hl = tid & 7;
        Whys[o][hl] = Why[(size_t)o * HID_ + h0 + hl];
    }
    __syncthreads();

    // ---- gates: thread = (hl, bg)  [round-3 proven body]
    {
        const int hl = tid & (HT - 1);
        const int bg = tid >> 3;
        const int h  = h0 + hl;
        const float* bx = dir ? bxb : bxf;
        const float* bh = dir ? bhb : bhf;
        float gi = bx[h]            + bh[h];
        float gg = bx[2 * HID_ + h] + bh[2 * HID_ + h];
        float go = bx[3 * HID_ + h] + bh[3 * HID_ + h];

        #pragma unroll 8
        for (int k4 = 0; k4 < EMB_ / 4; ++k4) {
            const float4 x  = *reinterpret_cast<const float4*>(&Xs[bg][4 * k4]);
            const float4 wi = *reinterpret_cast<const float4*>(&Ws[0][hl][4 * k4]);
            const float4 wg = *reinterpret_cast<const float4*>(&Ws[1][hl][4 * k4]);
            const float4 wo = *reinterpret_cast<const float4*>(&Ws[2][hl][4 * k4]);
            gi = fmaf(x.x, wi.x, fmaf(x.y, wi.y, fmaf(x.z, wi.z, fmaf(x.w, wi.w, gi))));
            gg = fmaf(x.x, wg.x, fmaf(x.y, wg.y, fmaf(x.z, wg.z, fmaf(x.w, wg.w, gg))));
            go = fmaf(x.x, wo.x, fmaf(x.y, wo.y, fmaf(x.z, wo.z, fmaf(x.w, wo.w, go))));
        }
        const float si = 1.0f / (1.0f + expf(-gi));
        const float so = 1.0f / (1.0f + expf(-go));
        hy_s[bg][hl] = so * tanhf(si * tanhf(gg));
    }
    __syncthreads();

    // ---- partial logits: contiguous 8KB per block, fully coalesced stores
    {
        const int sl64 = dir * 32 + ht;                       // 0..63
        float* base = pl + ((size_t)(sl64 * 2 + bhalf)) * (BH * OUT_);
        #pragma unroll
        for (int i = 0; i < 4; ++i) {
            const int p  = tid + 512 * i;      // 0..2047
            const int bl = p >> 5;
            const int o  = p & 31;
            float acc = 0.0f;
            #pragma unroll
            for (int hl = 0; hl < HT; ++hl)
                acc = fmaf(hy_s[bl][hl], Whys[o][hl], acc);
            base[p] = acc;
        }
    }

    // ---- grid spin-barrier: 128 blocks (<256 CUs, all co-resident -> safe).
    // One atomic per block + low-rate polling; no contended data atomics.
    __threadfence();
    __syncthreads();
    if (tid == 0) {
        atomicAdd(ctr, 1u);
        unsigned int v;
        do {
            __builtin_amdgcn_s_sleep(8);
            v = atomicAdd(ctr, 0u);
        } while (v < (unsigned int)NBLK);
        __threadfence();   // acquire before tail reads
    }
    __syncthreads();

    // ---- tail: block handles batch row b = blk. 8KB of reads, in parallel
    // across all 128 blocks.
    {
        const int b_t  = blk;
        const int bh_t = b_t >> 6;
        const int bl_t = b_t & 63;

        float4* red = reinterpret_cast<float4*>(&Xs[0][0]);   // red[64][8]
        const int sl = tid >> 3;        // 0..63
        const int o4 = tid & 7;         // 0..7
        red[sl * 8 + o4] = *reinterpret_cast<const float4*>(
            pl + ((size_t)(sl * 2 + bh_t) * BH + bl_t) * OUT_ + 4 * o4);
        __syncthreads();

        if (tid < 64) {                 // stage 1: 64 -> 8 slices
            const int s = tid >> 3, q = tid & 7;
            float4 a = red[s * 8 + q];
            #pragma unroll
            for (int j = 1; j < 8; ++j) {
                const float4 v = red[(s + 8 * j) * 8 + q];
                a.x += v.x; a.y += v.y; a.z += v.z; a.w += v.w;
            }
            red[s * 8 + q] = a;
        }
        __syncthreads();
        if (tid < 8) {                  // stage 2: 8 -> 1, add by
            float4 a = red[tid];
            #pragma unroll
            for (int s = 1; s < 8; ++s) {
                const float4 v = red[s * 8 + tid];
                a.x += v.x; a.y += v.y; a.z += v.z; a.w += v.w;
            }
            lg[4 * tid + 0] = a.x + by[4 * tid + 0];
            lg[4 * tid + 1] = a.y + by[4 * tid + 1];
            lg[4 * tid + 2] = a.z + by[4 * tid + 2];
            lg[4 * tid + 3] = a.w + by[4 * tid + 3];
        }
        __syncthreads();
        if (tid < OUT_) {               // 32-wide log-softmax, lanes 0..31
            const float v = lg[tid];
            float m = v;
            #pragma unroll
            for (int off = 16; off; off >>= 1) m = fmaxf(m, __shfl_xor(m, off));
            float s = expf(v - m);
            #pragma unroll
            for (int off = 16; off; off >>= 1) s += __shfl_xor(s, off);
            out[(size_t)b_t * OUT_ + tid] = v - m - logf(s);
        }
    }
}

extern "C" void kernel_launch(void* const* d_in, const int* in_sizes, int n_in,
                              void* d_out, int out_size, void* d_ws, size_t ws_size,
                              hipStream_t stream) {
    // setup_inputs() order:
    // 0 inputs [B,S] int32      1 weight [VOCAB,EMB] f32
    // 2 Wxf [1024,128]  3 bxf [1024]  4 Whf (dead)  5 bhf [1024]
    // 6 Wxb [1024,128]  7 bxb [1024]  8 Whb (dead)  9 bhb [1024]
    // 10 Why [32,256]   11 by [32]
    const int*   inputs = (const int*)  d_in[0];
    const float* weight = (const float*)d_in[1];
    const float* Wxf    = (const float*)d_in[2];
    const float* bxf    = (const float*)d_in[3];
    const float* bhf    = (const float*)d_in[5];
    const float* Wxb    = (const float*)d_in[6];
    const float* bxb    = (const float*)d_in[7];
    const float* bhb    = (const float*)d_in[9];
    const float* Why    = (const float*)d_in[10];
    const float* by     = (const float*)d_in[11];
    float* out = (float*)d_out;

    float*        pl  = (float*)d_ws;
    unsigned int* ctr = (unsigned int*)((char*)d_ws + CTR_OFF);

    // Exact-arrival barrier counter: zero 4 bytes each call (graph-legal).
    hipMemsetAsync(ctr, 0, sizeof(unsigned int), stream);

    bilstm_one<<<NBLK, 512, 0, stream>>>(inputs, weight,
                                         Wxf, bxf, bhf,
                                         Wxb, bxb, bhb,
                                         Why, by, pl, ctr, out);
}

// Round 8
// 24.546 us; speedup vs baseline: 1.6891x; 1.6891x over previous
//
#include <hip/hip_runtime.h>
#include <math.h>

// Problem constants (from the reference file)
constexpr int B_   = 128;
constexpr int S_   = 2048;
constexpr int EMB_ = 128;
constexpr int HID_ = 256;
constexpr int OUT_ = 32;

// One block per batch element; 512 threads = 8 waves = 32 sixteen-lane groups.
// Each block computes BOTH directions' gates (768 useful rows per dir: i,g,o;
// the f-gate is dead since c=0), the combined hy, logits and log-softmax —
// no workspace, no cross-block communication, single dispatch.
__global__ __launch_bounds__(512) void bilstm_all(
    const int*   __restrict__ inputs,
    const float* __restrict__ weight,
    const float* __restrict__ Wxf, const float* __restrict__ bxf, const float* __restrict__ bhf,
    const float* __restrict__ Wxb, const float* __restrict__ bxb, const float* __restrict__ bhb,
    const float* __restrict__ Why, const float* __restrict__ by,
    float*       __restrict__ out)
{
    __shared__ float gd[2][3][HID_];   // row-dot results: [dir][gate i/g/o][h]
    __shared__ __align__(16) float hv[2][HID_];
    __shared__ float lg[OUT_];
    __shared__ int   toks[2];

    const int b    = blockIdx.x;
    const int tid  = threadIdx.x;
    const int wave = tid >> 6;
    const int lane = tid & 63;
    const int sub  = lane >> 4;         // 16-lane group within wave
    const int l16  = lane & 15;
    const int G    = wave * 4 + sub;    // global group id 0..31

    if (tid < 2) toks[tid] = inputs[(size_t)b * S_ + (tid ? 0 : (S_ - 1))];
    __syncthreads();

    // x for both directions in registers: 8 floats per lane (cols l16*8..+8).
    const float4* xfp = reinterpret_cast<const float4*>(weight + (size_t)toks[0] * EMB_);
    const float4* xbp = reinterpret_cast<const float4*>(weight + (size_t)toks[1] * EMB_);
    const float4 xf0 = xfp[2 * l16], xf1 = xfp[2 * l16 + 1];
    const float4 xb0 = xbp[2 * l16], xb1 = xbp[2 * l16 + 1];

    // ---- stream gate rows from L2: group G handles rows u = G + 32*j.
    // u in [0,768): gs = u>>8 selects gate (0->i row 0.., 1->g rows 512..,
    // 2->o rows 768..), h = u&255. 4 groups of a wave read 4 consecutive
    // rows -> 2KB contiguous per wave-instruction pair (fully coalesced).
    {
        const float* W = Wxf;
        #pragma unroll 4
        for (int j = 0; j < 24; ++j) {
            const int u    = G + 32 * j;
            const int gs   = u >> 8;
            const int h    = u & 255;
            const int grow = (gs == 0) ? 0 : (gs + 1);   // i->0, g->2, o->3
            const float4* r = reinterpret_cast<const float4*>(
                W + ((size_t)grow * HID_ + h) * EMB_);
            const float4 a = r[2 * l16];
            const float4 c = r[2 * l16 + 1];
            float p = a.x * xf0.x + a.y * xf0.y + a.z * xf0.z + a.w * xf0.w
                    + c.x * xf1.x + c.y * xf1.y + c.z * xf1.z + c.w * xf1.w;
            p += __shfl_xor(p, 1);
            p += __shfl_xor(p, 2);
            p += __shfl_xor(p, 4);
            p += __shfl_xor(p, 8);
            if (l16 == 0) gd[0][gs][h] = p;
        }
    }
    {
        const float* W = Wxb;
        #pragma unroll 4
        for (int j = 0; j < 24; ++j) {
            const int u    = G + 32 * j;
            const int gs   = u >> 8;
            const int h    = u & 255;
            const int grow = (gs == 0) ? 0 : (gs + 1);
            const float4* r = reinterpret_cast<const float4*>(
                W + ((size_t)grow * HID_ + h) * EMB_);
            const float4 a = r[2 * l16];
            const float4 c = r[2 * l16 + 1];
            float p = a.x * xb0.x + a.y * xb0.y + a.z * xb0.z + a.w * xb0.w
                    + c.x * xb1.x + c.y * xb1.y + c.z * xb1.z + c.w * xb1.w;
            p += __shfl_xor(p, 1);
            p += __shfl_xor(p, 2);
            p += __shfl_xor(p, 4);
            p += __shfl_xor(p, 8);
            if (l16 == 0) gd[1][gs][h] = p;
        }
    }
    __syncthreads();

    // ---- gate math: thread t = (dir, h); bias loads are coalesced.
    {
        const int dir = tid >> 8;
        const int h   = tid & 255;
        const float* bx = dir ? bxb : bxf;
        const float* bh = dir ? bhb : bhf;
        const float gi = gd[dir][0][h] + bx[h]            + bh[h];
        const float gg = gd[dir][1][h] + bx[2 * HID_ + h] + bh[2 * HID_ + h];
        const float go = gd[dir][2][h] + bx[3 * HID_ + h] + bh[3 * HID_ + h];
        const float si = 1.0f / (1.0f + expf(-gi));
        const float so = 1.0f / (1.0f + expf(-go));
        hv[dir][h] = so * tanhf(si * tanhf(gg));
    }
    __syncthreads();

    // ---- logits: wave w handles o = w, w+8, w+16, w+24 (64-lane dot over 256).
    #pragma unroll
    for (int i = 0; i < 4; ++i) {
        const int o = wave + 8 * i;
        const float4 wv = reinterpret_cast<const float4*>(Why + (size_t)o * HID_)[lane];
        const float4 h0 = *reinterpret_cast<const float4*>(&hv[0][4 * lane]);
        const float4 h1 = *reinterpret_cast<const float4*>(&hv[1][4 * lane]);
        float p = wv.x * (h0.x + h1.x) + wv.y * (h0.y + h1.y)
                + wv.z * (h0.z + h1.z) + wv.w * (h0.w + h1.w);
        #pragma unroll
        for (int off = 32; off; off >>= 1) p += __shfl_xor(p, off);
        if (lane == 0) lg[o] = p + by[o];
    }
    __syncthreads();

    // ---- 32-wide log-softmax (lanes 0..31 of wave 0), coalesced 128B store.
    if (tid < OUT_) {
        const float v = lg[tid];
        float m = v;
        #pragma unroll
        for (int off = 16; off; off >>= 1) m = fmaxf(m, __shfl_xor(m, off));
        float s = expf(v - m);
        #pragma unroll
        for (int off = 16; off; off >>= 1) s += __shfl_xor(s, off);
        out[(size_t)b * OUT_ + tid] = v - m - logf(s);
    }
}

extern "C" void kernel_launch(void* const* d_in, const int* in_sizes, int n_in,
                              void* d_out, int out_size, void* d_ws, size_t ws_size,
                              hipStream_t stream) {
    // setup_inputs() order:
    // 0 inputs [B,S] int32      1 weight [VOCAB,EMB] f32
    // 2 Wxf [1024,128]  3 bxf [1024]  4 Whf (dead)  5 bhf [1024]
    // 6 Wxb [1024,128]  7 bxb [1024]  8 Whb (dead)  9 bhb [1024]
    // 10 Why [32,256]   11 by [32]
    const int*   inputs = (const int*)  d_in[0];
    const float* weight = (const float*)d_in[1];
    const float* Wxf    = (const float*)d_in[2];
    const float* bxf    = (const float*)d_in[3];
    const float* bhf    = (const float*)d_in[5];
    const float* Wxb    = (const float*)d_in[6];
    const float* bxb    = (const float*)d_in[7];
    const float* bhb    = (const float*)d_in[9];
    const float* Why    = (const float*)d_in[10];
    const float* by     = (const float*)d_in[11];
    float* out = (float*)d_out;

    // Single dispatch. No workspace, no memset, no cross-block sync.
    bilstm_all<<<B_, 512, 0, stream>>>(inputs, weight,
                                       Wxf, bxf, bhf,
                                       Wxb, bxb, bhb,
                                       Why, by, out);
}